// Round 9
// baseline (660.583 us; speedup 1.0000x reference)
//
#include <hip/hip_runtime.h>

#define NH     16
#define SEQ    2048
#define DMODEL 1024
#define DK     64
#define NB     4

typedef __attribute__((ext_vector_type(8))) short short8v;   // 8 bf16
typedef __attribute__((ext_vector_type(4))) short short4v;   // 4 bf16
typedef __attribute__((ext_vector_type(4))) float f32x4;

// exp(x*0.125) == exp2(x * 0.125*log2(e))
#define EXP_SC 0.18033688011f

__device__ __forceinline__ short f2bf(float x) {
  unsigned u = __float_as_uint(x);
  unsigned r = (u + 0x7FFFu + ((u >> 16) & 1u)) >> 16;
  return (short)r;
}
__device__ __forceinline__ float bf2f(short b) {
  return __uint_as_float(((unsigned)(unsigned short)b) << 16);
}

// async global->LDS, 16 B per lane (dest = wave-uniform base + lane*16)
typedef const __attribute__((address_space(1))) unsigned int* gas_t;
typedef __attribute__((address_space(3))) unsigned int* las_t;
__device__ __forceinline__ void glds16(const void* g, void* l) {
  __builtin_amdgcn_global_load_lds((gas_t)g, (las_t)l, 16, 0, 0);
}

// ---- 256-thread (4-wave) stagers ------------------------------------------
__device__ __forceinline__ void stage_tile(const void* grow0, int gpitchB,
                                           void* ltile, int wid, int lane) {
#pragma unroll
  for (int i = 0; i < 2; ++i) {
    const int row = i * 32 + wid * 8 + (lane >> 3);
    const int srccol = ((lane & 7) * 16) ^ ((lane >> 3) << 4);  // row&7 == lane>>3
    const char* src = reinterpret_cast<const char*>(grow0) + (size_t)row * gpitchB + srccol;
    char* dst = reinterpret_cast<char*>(ltile) + i * 4096 + wid * 1024;
    glds16(src, dst);
  }
}

// ---- 512-thread (8-wave) stagers ------------------------------------------
__device__ __forceinline__ void stage_tile_h8(const void* grow0, int gpitchB,
                                              void* ltile, int wid, int lane) {
  const int row = wid * 8 + (lane >> 3);
  const int srccol = ((lane & 7) * 16) ^ ((lane >> 3) << 4);
  const char* src = reinterpret_cast<const char*>(grow0) + (size_t)row * gpitchB + srccol;
  char* dst = reinterpret_cast<char*>(ltile) + wid * 1024;
  glds16(src, dst);
}
__device__ __forceinline__ void stage_tile128(const void* grow0, int gpitchB,
                                              void* ltile, int wid, int lane) {
#pragma unroll
  for (int i = 0; i < 2; ++i) {
    const int row = i * 64 + wid * 8 + (lane >> 3);
    const int srccol = ((lane & 7) * 16) ^ ((lane >> 3) << 4);
    const char* src = reinterpret_cast<const char*>(grow0) + (size_t)row * gpitchB + srccol;
    char* dst = reinterpret_cast<char*>(ltile) + i * 8192 + wid * 1024;
    glds16(src, dst);
  }
}

// swizzled LDS accessors for [*][64] bf16 tiles (row pitch 128 B)
__device__ __forceinline__ short8v ldfrag(const short* base, int row, int colByte) {
  return *reinterpret_cast<const short8v*>(
      reinterpret_cast<const char*>(base) + row * 128 + (colByte ^ ((row & 7) << 4)));
}
__device__ __forceinline__ void st8b(short* base, int row, int colByte, short4v v) {
  *reinterpret_cast<short4v*>(
      reinterpret_cast<char*>(base) + row * 128 + (colByte ^ ((row & 7) << 4))) = v;
}

// ===========================================================================
// pack_mask: [B,S,S] int -> [B,S,S/64] uint64 bitmask
// ===========================================================================
__global__ __launch_bounds__(256) void pack_mask_kernel(
    const int* __restrict__ mask, unsigned long long* __restrict__ bits)
{
  const int t = threadIdx.x;
  const size_t chunk = (size_t)blockIdx.x * 4 + (t >> 6);
  const int lane = t & 63;
  const int m = mask[chunk * 64 + lane];
  const unsigned long long b = __ballot(m != 0);
  if (lane == 0) bits[chunk] = b;
}

// ===========================================================================
// convert fp32 -> bf16 (flat, 8 elems/thread)
// ===========================================================================
__global__ __launch_bounds__(256) void convert_f32_bf16_kernel(
    const float* __restrict__ in, short* __restrict__ out)
{
  const int idx = blockIdx.x * 256 + threadIdx.x;
  const float4 x0 = *reinterpret_cast<const float4*>(&in[(size_t)idx * 8]);
  const float4 x1 = *reinterpret_cast<const float4*>(&in[(size_t)idx * 8 + 4]);
  short8v o;
  o[0] = f2bf(x0.x); o[1] = f2bf(x0.y); o[2] = f2bf(x0.z); o[3] = f2bf(x0.w);
  o[4] = f2bf(x1.x); o[5] = f2bf(x1.y); o[6] = f2bf(x1.z); o[7] = f2bf(x1.w);
  *reinterpret_cast<short8v*>(&out[(size_t)idx * 8]) = o;
}

// ===========================================================================
// transpose all W: z=0..2 -> WT bf16; z=3 -> WTh/WTl hi-lo split (Wo)
// ===========================================================================
__global__ __launch_bounds__(256) void transpose_w_all_kernel(
    const float* __restrict__ W0, const float* __restrict__ W1,
    const float* __restrict__ W2, const float* __restrict__ W3,
    short* __restrict__ WT0, short* __restrict__ WT1,
    short* __restrict__ WT2, short* __restrict__ WT3h, short* __restrict__ WT3l)
{
  __shared__ short Th[64][80];
  __shared__ short Tl[64][80];
  const int t  = threadIdx.x;
  const int k0 = blockIdx.x * 64;
  const int n0 = blockIdx.y * 64;
  const int z  = blockIdx.z;
  const float* W = (z == 0) ? W0 : (z == 1) ? W1 : (z == 2) ? W2 : W3;

  const int kl = t >> 2, nc = (t & 3) * 16;
  if (z < 3) {
#pragma unroll
    for (int i = 0; i < 4; ++i) {
      const float4 x = *reinterpret_cast<const float4*>(&W[(size_t)(k0 + kl) * DMODEL + n0 + nc + i * 4]);
      Th[nc + i * 4 + 0][kl] = f2bf(x.x);
      Th[nc + i * 4 + 1][kl] = f2bf(x.y);
      Th[nc + i * 4 + 2][kl] = f2bf(x.z);
      Th[nc + i * 4 + 3][kl] = f2bf(x.w);
    }
    __syncthreads();
    short* WT = (z == 0) ? WT0 : (z == 1) ? WT1 : WT2;
    const int nl = t >> 2, kc = (t & 3) * 16;
#pragma unroll
    for (int i = 0; i < 2; ++i) {
      const short8v y = *reinterpret_cast<const short8v*>(&Th[nl][kc + i * 8]);
      *reinterpret_cast<short8v*>(&WT[(size_t)(n0 + nl) * DMODEL + k0 + kc + i * 8]) = y;
    }
  } else {
#pragma unroll
    for (int i = 0; i < 4; ++i) {
      const float4 x = *reinterpret_cast<const float4*>(&W[(size_t)(k0 + kl) * DMODEL + n0 + nc + i * 4]);
      const float xv[4] = {x.x, x.y, x.z, x.w};
#pragma unroll
      for (int j = 0; j < 4; ++j) {
        const short hi = f2bf(xv[j]);
        const short lo = f2bf(xv[j] - bf2f(hi));
        Th[nc + i * 4 + j][kl] = hi;
        Tl[nc + i * 4 + j][kl] = lo;
      }
    }
    __syncthreads();
    const int nl = t >> 2, kc = (t & 3) * 16;
#pragma unroll
    for (int i = 0; i < 2; ++i) {
      const short8v yh = *reinterpret_cast<const short8v*>(&Th[nl][kc + i * 8]);
      const short8v yl = *reinterpret_cast<const short8v*>(&Tl[nl][kc + i * 8]);
      *reinterpret_cast<short8v*>(&WT3h[(size_t)(n0 + nl) * DMODEL + k0 + kc + i * 8]) = yh;
      *reinterpret_cast<short8v*>(&WT3l[(size_t)(n0 + nl) * DMODEL + k0 + kc + i * 8]) = yl;
    }
  }
}

// ===========================================================================
// proj MFMA GEMM. 1-D grid, n-fastest + XCD-chunked swizzle.
// ===========================================================================
__global__ __launch_bounds__(256) void proj_mfma_kernel(
    const short* __restrict__ A,   // [8192][1024] bf16
    const short* __restrict__ BT,  // [1024][1024] bf16 (row n = W col n)
    const float* __restrict__ bias,
    short* __restrict__ out)       // [B,H,S,DK] bf16
{
  __shared__ short As[128 * 64];
  __shared__ short Bs[128 * 64];

  const int t = threadIdx.x, lane = t & 63, wid = t >> 6;
  const int g = lane >> 4, r15 = lane & 15;
  const int lid = (blockIdx.x & 7) * 64 + (blockIdx.x >> 3);
  const int m0 = (lid >> 3) * 128, n0 = (lid & 7) * 128;
  const int wm = (wid >> 1) * 64, wn = (wid & 1) * 64;

  f32x4 acc[4][4];
#pragma unroll
  for (int i = 0; i < 4; ++i)
#pragma unroll
    for (int j = 0; j < 4; ++j) acc[i][j] = (f32x4){0.f, 0.f, 0.f, 0.f};

  for (int k0 = 0; k0 < DMODEL; k0 += 64) {
    __syncthreads();
    stage_tile(A + (size_t)m0 * DMODEL + k0, DMODEL * 2, As, wid, lane);
    stage_tile(A + (size_t)(m0 + 64) * DMODEL + k0, DMODEL * 2, As + 64 * 64, wid, lane);
    stage_tile(BT + (size_t)n0 * DMODEL + k0, DMODEL * 2, Bs, wid, lane);
    stage_tile(BT + (size_t)(n0 + 64) * DMODEL + k0, DMODEL * 2, Bs + 64 * 64, wid, lane);
    __syncthreads();

#pragma unroll
    for (int w = 0; w < 2; ++w) {
      short8v a[4], b[4];
#pragma unroll
      for (int i = 0; i < 4; ++i) a[i] = ldfrag(As, wm + i * 16 + r15, w * 64 + g * 16);
#pragma unroll
      for (int j = 0; j < 4; ++j) b[j] = ldfrag(Bs, wn + j * 16 + r15, w * 64 + g * 16);
#pragma unroll
      for (int i = 0; i < 4; ++i)
#pragma unroll
        for (int j = 0; j < 4; ++j)
          acc[i][j] = __builtin_amdgcn_mfma_f32_16x16x32_bf16(a[i], b[j], acc[i][j], 0, 0, 0);
    }
  }

#pragma unroll
  for (int j = 0; j < 4; ++j) {
    const int n = n0 + wn + j * 16 + r15;
    const int hh = n >> 6, dd = n & 63;
    const float bv = bias[n];
#pragma unroll
    for (int i = 0; i < 4; ++i) {
#pragma unroll
      for (int reg = 0; reg < 4; ++reg) {
        const int m = m0 + wm + i * 16 + g * 4 + reg;
        const int bb = m >> 11, ss = m & 2047;
        out[((size_t)(bb * NH + hh) * SEQ + ss) * DK + dd] = f2bf(acc[i][j][reg] + bv);
      }
    }
  }
}

// ===========================================================================
// outproj bf16x3 MFMA. Same 1-D chunked grid as proj.
// ===========================================================================
__global__ __launch_bounds__(256) void outproj_mfma_kernel(
    const short* __restrict__ Ahp, const short* __restrict__ Alp,
    const short* __restrict__ BTh, const short* __restrict__ BTl,
    const float* __restrict__ bias, float* __restrict__ out)
{
  __shared__ short Ah[128 * 64];
  __shared__ short Al[128 * 64];
  __shared__ short Bh[128 * 64];
  __shared__ short Bl[128 * 64];

  const int t = threadIdx.x, lane = t & 63, wid = t >> 6;
  const int g = lane >> 4, r15 = lane & 15;
  const int lid = (blockIdx.x & 7) * 64 + (blockIdx.x >> 3);
  const int m0 = (lid >> 3) * 128, n0 = (lid & 7) * 128;
  const int wm = (wid >> 1) * 64, wn = (wid & 1) * 64;

  f32x4 acc[4][4];
#pragma unroll
  for (int i = 0; i < 4; ++i)
#pragma unroll
    for (int j = 0; j < 4; ++j) acc[i][j] = (f32x4){0.f, 0.f, 0.f, 0.f};

  for (int k0 = 0; k0 < DMODEL; k0 += 64) {
    __syncthreads();
    stage_tile(Ahp + (size_t)m0 * DMODEL + k0, DMODEL * 2, Ah, wid, lane);
    stage_tile(Ahp + (size_t)(m0 + 64) * DMODEL + k0, DMODEL * 2, Ah + 64 * 64, wid, lane);
    stage_tile(Alp + (size_t)m0 * DMODEL + k0, DMODEL * 2, Al, wid, lane);
    stage_tile(Alp + (size_t)(m0 + 64) * DMODEL + k0, DMODEL * 2, Al + 64 * 64, wid, lane);
    stage_tile(BTh + (size_t)n0 * DMODEL + k0, DMODEL * 2, Bh, wid, lane);
    stage_tile(BTh + (size_t)(n0 + 64) * DMODEL + k0, DMODEL * 2, Bh + 64 * 64, wid, lane);
    stage_tile(BTl + (size_t)n0 * DMODEL + k0, DMODEL * 2, Bl, wid, lane);
    stage_tile(BTl + (size_t)(n0 + 64) * DMODEL + k0, DMODEL * 2, Bl + 64 * 64, wid, lane);
    __syncthreads();

#pragma unroll
    for (int w = 0; w < 2; ++w) {
      short8v ah[4], al[4];
#pragma unroll
      for (int i = 0; i < 4; ++i) {
        ah[i] = ldfrag(Ah, wm + i * 16 + r15, w * 64 + g * 16);
        al[i] = ldfrag(Al, wm + i * 16 + r15, w * 64 + g * 16);
      }
#pragma unroll
      for (int j = 0; j < 4; ++j) {
        const short8v bh = ldfrag(Bh, wn + j * 16 + r15, w * 64 + g * 16);
        const short8v bl = ldfrag(Bl, wn + j * 16 + r15, w * 64 + g * 16);
#pragma unroll
        for (int i = 0; i < 4; ++i) {
          acc[i][j] = __builtin_amdgcn_mfma_f32_16x16x32_bf16(ah[i], bh, acc[i][j], 0, 0, 0);
          acc[i][j] = __builtin_amdgcn_mfma_f32_16x16x32_bf16(ah[i], bl, acc[i][j], 0, 0, 0);
          acc[i][j] = __builtin_amdgcn_mfma_f32_16x16x32_bf16(al[i], bh, acc[i][j], 0, 0, 0);
        }
      }
    }
  }

#pragma unroll
  for (int j = 0; j < 4; ++j) {
    const int n = n0 + wn + j * 16 + r15;
    const float bv = bias[n];
#pragma unroll
    for (int i = 0; i < 4; ++i)
#pragma unroll
      for (int reg = 0; reg < 4; ++reg) {
        const int m = m0 + wm + i * 16 + g * 4 + reg;
        out[(size_t)m * DMODEL + n] = acc[i][j][reg] + bv;
      }
  }
}

// ===========================================================================
// transpose V: vhb [head][s][d] -> vT [head][d][s]   (bf16)
// ===========================================================================
__global__ __launch_bounds__(256) void transpose_v_kernel(
    const short* __restrict__ vhb, short* __restrict__ vT)
{
  __shared__ short T[64][72];
  const int t    = threadIdx.x;
  const int s0   = blockIdx.x * 64;
  const int head = blockIdx.y;
  const size_t ibase = (size_t)head * SEQ * DK;
  const size_t obase = (size_t)head * DK * SEQ;

  const int sl = t >> 2, d0 = (t & 3) * 16;
#pragma unroll
  for (int i = 0; i < 2; ++i) {
    const short8v x = *reinterpret_cast<const short8v*>(
        &vhb[ibase + (size_t)(s0 + sl) * DK + d0 + i * 8]);
#pragma unroll
    for (int j = 0; j < 8; ++j) T[d0 + i * 8 + j][sl] = x[j];
  }
  __syncthreads();
  const int dl = t >> 2, soff = (t & 3) * 16;
#pragma unroll
  for (int i = 0; i < 2; ++i) {
    const short8v y = *reinterpret_cast<const short8v*>(&T[dl][soff + i * 8]);
    *reinterpret_cast<short8v*>(&vT[obase + (size_t)dl * SEQ + s0 + soff + i * 8]) = y;
  }
}

// ===========================================================================
// flash_kernel: QBLK=128, 8 waves, m==0 single pass, K/V dbuf, XCD swizzle.
// ===========================================================================
__global__ __launch_bounds__(512) void flash_kernel(
    const short* __restrict__ qh, const short* __restrict__ kh,
    const short* __restrict__ vT, const unsigned long long* __restrict__ maskbits,
    short* __restrict__ ctxh, short* __restrict__ ctxl,
    float* __restrict__ linv_arr)
{
  __shared__ short Qs[128 * 64];      // 16 KB
  __shared__ short Ks[2][64 * 64];    // 16 KB
  __shared__ short VsT[2][64 * 64];   // 16 KB
  __shared__ short Psb[128 * 64];     // 16 KB (wave-private rows)

  const int t    = threadIdx.x;
  const int lane = t & 63;
  const int wid  = t >> 6;            // 0..7
  const int g    = lane >> 4;
  const int r15  = lane & 15;
  const int qbase = wid * 16;
  const int qrow  = qbase + r15;

  const int bid = blockIdx.x;
  const int swz = (bid & 7) * 128 + (bid >> 3);
  const int qt = swz & 15;
  const int h  = (swz >> 4) & 15;
  const int b  = swz >> 8;
  const int q0 = qt * 128;

  const size_t headbase = ((size_t)(b * NH + h)) * SEQ * DK;
  const size_t vTbase   = ((size_t)(b * NH + h)) * DK * SEQ;
  const size_t mrow     = ((size_t)b * SEQ + (q0 + qrow)) * (SEQ / 64);

  stage_tile128(qh + headbase + (size_t)q0 * DK, DK * 2, Qs, wid, lane);
  stage_tile_h8(kh + headbase, DK * 2, Ks[0], wid, lane);
  stage_tile_h8(reinterpret_cast<const char*>(vT + vTbase), SEQ * 2, VsT[0], wid, lane);
  asm volatile("s_waitcnt vmcnt(0)" ::: "memory");
  __builtin_amdgcn_s_barrier();

  const short8v bQ0 = ldfrag(Qs, qrow, g * 16);
  const short8v bQ1 = ldfrag(Qs, qrow, 64 + g * 16);

  float lsum = 0.f;
  f32x4 cacc[4];
#pragma unroll
  for (int i = 0; i < 4; ++i) cacc[i] = (f32x4){0.f, 0.f, 0.f, 0.f};

  for (int t64 = 0; t64 < 32; ++t64) {
    const int cur = t64 & 1;
    if (t64 < 31) {
      stage_tile_h8(kh + headbase + (size_t)(t64 + 1) * 64 * DK, DK * 2,
                    Ks[cur ^ 1], wid, lane);
      stage_tile_h8(reinterpret_cast<const char*>(vT + vTbase + (t64 + 1) * 64), SEQ * 2,
                    VsT[cur ^ 1], wid, lane);
    }
    __builtin_amdgcn_sched_barrier(0);

    f32x4 acc[4];
#pragma unroll
    for (int t4 = 0; t4 < 4; ++t4) acc[t4] = (f32x4){0.f, 0.f, 0.f, 0.f};
#pragma unroll
    for (int t4 = 0; t4 < 4; ++t4) {
      const short8v aK0 = ldfrag(Ks[cur], t4 * 16 + r15, g * 16);
      const short8v aK1 = ldfrag(Ks[cur], t4 * 16 + r15, 64 + g * 16);
      acc[t4] = __builtin_amdgcn_mfma_f32_16x16x32_bf16(aK0, bQ0, acc[t4], 0, 0, 0);
      acc[t4] = __builtin_amdgcn_mfma_f32_16x16x32_bf16(aK1, bQ1, acc[t4], 0, 0, 0);
    }

    const unsigned long long mb = maskbits[mrow + t64];
    if (__all(mb == ~0ULL)) {
#pragma unroll
      for (int t4 = 0; t4 < 4; ++t4) {
        short4v pk;
#pragma unroll
        for (int reg = 0; reg < 4; ++reg) {
          const float p = exp2f(acc[t4][reg] * EXP_SC);
          lsum += p;
          pk[reg] = f2bf(p);
        }
        st8b(Psb, qrow, t4 * 32 + g * 8, pk);
      }
    } else {
#pragma unroll
      for (int t4 = 0; t4 < 4; ++t4) {
        const unsigned b4 = (unsigned)(mb >> (t4 * 16 + g * 4)) & 0xFu;
        short4v pk;
#pragma unroll
        for (int reg = 0; reg < 4; ++reg) {
          const float p = ((b4 >> reg) & 1u) ? exp2f(acc[t4][reg] * EXP_SC) : 0.f;
          lsum += p;
          pk[reg] = f2bf(p);
        }
        st8b(Psb, qrow, t4 * 32 + g * 8, pk);
      }
    }

    // PV (Psb rows are wave-private)
    {
      const short8v aP0 = ldfrag(Psb, qrow, g * 16);
      const short8v aP1 = ldfrag(Psb, qrow, 64 + g * 16);
#pragma unroll
      for (int dt = 0; dt < 4; ++dt) {
        const short8v bV0 = ldfrag(VsT[cur], dt * 16 + r15, g * 16);
        const short8v bV1 = ldfrag(VsT[cur], dt * 16 + r15, 64 + g * 16);
        cacc[dt] = __builtin_amdgcn_mfma_f32_16x16x32_bf16(aP0, bV0, cacc[dt], 0, 0, 0);
        cacc[dt] = __builtin_amdgcn_mfma_f32_16x16x32_bf16(aP1, bV1, cacc[dt], 0, 0, 0);
      }
    }

    asm volatile("s_waitcnt vmcnt(0)" ::: "memory");
    __builtin_amdgcn_s_barrier();
  }

  float l = lsum;
  l += __shfl_xor(l, 16);
  l += __shfl_xor(l, 32);
  const float linv = 1.0f / l;
  if (g == 0)
    linv_arr[(size_t)(b * NH + h) * SEQ + q0 + qrow] = linv;

  float linvr[4];
#pragma unroll
  for (int reg = 0; reg < 4; ++reg) linvr[reg] = __shfl(linv, g * 4 + reg);

#pragma unroll
  for (int dt = 0; dt < 4; ++dt)
#pragma unroll
    for (int reg = 0; reg < 4; ++reg) {
      const float x = cacc[dt][reg] * linvr[reg];
      const short hi = f2bf(x);
      const short lo = f2bf(x - bf2f(hi));
      const size_t off = (size_t)(b * SEQ + q0 + qbase + g * 4 + reg) * DMODEL
                       + h * DK + dt * 16 + r15;
      ctxh[off] = hi;
      ctxl[off] = lo;
    }
}

// ===========================================================================
// probs_kernel: QBLK=128, 8 waves. p = exp2(fma(s, c, log2(linv))),
// stored DIRECTLY from acc regs (no LDS bounce): lane's float4 covers
// P[qrow][t64*64 + t4*16 + g*4 .. +3]; 4 g-lanes tile 64 B chunks.
// ===========================================================================
__global__ __launch_bounds__(512) void probs_kernel(
    const short* __restrict__ qh, const short* __restrict__ kh,
    const unsigned long long* __restrict__ maskbits,
    const float* __restrict__ linv_arr,
    float* __restrict__ attn_out)
{
  __shared__ short Qs[128 * 64];     // 16 KB
  __shared__ short Ks[2][64 * 64];   // 16 KB

  const int t    = threadIdx.x;
  const int lane = t & 63;
  const int wid  = t >> 6;           // 0..7
  const int g    = lane >> 4;
  const int r15  = lane & 15;
  const int qbase = wid * 16;
  const int qrow  = qbase + r15;

  const int bid = blockIdx.x;
  const int swz = (bid & 7) * 128 + (bid >> 3);
  const int qt = swz & 15;
  const int h  = (swz >> 4) & 15;
  const int b  = swz >> 8;
  const int q0 = qt * 128;

  const size_t headbase = ((size_t)(b * NH + h)) * SEQ * DK;
  const size_t attnbase = ((size_t)(b * NH + h)) * SEQ * SEQ;
  const size_t mrow     = ((size_t)b * SEQ + (q0 + qrow)) * (SEQ / 64);

  const float linv  = linv_arr[(size_t)(b * NH + h) * SEQ + q0 + qrow];
  const float llinv = log2f(linv);

  float* prow_out = attn_out + attnbase + (size_t)(q0 + qrow) * SEQ + g * 4;

  stage_tile128(qh + headbase + (size_t)q0 * DK, DK * 2, Qs, wid, lane);
  stage_tile_h8(kh + headbase, DK * 2, Ks[0], wid, lane);
  asm volatile("s_waitcnt vmcnt(0)" ::: "memory");
  __builtin_amdgcn_s_barrier();

  const short8v bQ0 = ldfrag(Qs, qrow, g * 16);
  const short8v bQ1 = ldfrag(Qs, qrow, 64 + g * 16);

  for (int t64 = 0; t64 < 32; ++t64) {
    const int cur = t64 & 1;
    if (t64 + 1 < 32)
      stage_tile_h8(kh + headbase + (size_t)(t64 + 1) * 64 * DK, DK * 2,
                    Ks[cur ^ 1], wid, lane);
    __builtin_amdgcn_sched_barrier(0);

    f32x4 acc[4];
#pragma unroll
    for (int t4 = 0; t4 < 4; ++t4) acc[t4] = (f32x4){0.f, 0.f, 0.f, 0.f};
#pragma unroll
    for (int t4 = 0; t4 < 4; ++t4) {
      const short8v aK0 = ldfrag(Ks[cur], t4 * 16 + r15, g * 16);
      const short8v aK1 = ldfrag(Ks[cur], t4 * 16 + r15, 64 + g * 16);
      acc[t4] = __builtin_amdgcn_mfma_f32_16x16x32_bf16(aK0, bQ0, acc[t4], 0, 0, 0);
      acc[t4] = __builtin_amdgcn_mfma_f32_16x16x32_bf16(aK1, bQ1, acc[t4], 0, 0, 0);
    }

    const unsigned long long mb = maskbits[mrow + t64];
    if (__all(mb == ~0ULL)) {
#pragma unroll
      for (int t4 = 0; t4 < 4; ++t4) {
        f32x4 pv;
        pv[0] = exp2f(fmaf(acc[t4][0], EXP_SC, llinv));
        pv[1] = exp2f(fmaf(acc[t4][1], EXP_SC, llinv));
        pv[2] = exp2f(fmaf(acc[t4][2], EXP_SC, llinv));
        pv[3] = exp2f(fmaf(acc[t4][3], EXP_SC, llinv));
        __builtin_nontemporal_store(pv, reinterpret_cast<f32x4*>(
            prow_out + t64 * 64 + t4 * 16));
      }
    } else {
#pragma unroll
      for (int t4 = 0; t4 < 4; ++t4) {
        const unsigned b4 = (unsigned)(mb >> (t4 * 16 + g * 4)) & 0xFu;
        f32x4 pv;
        pv[0] = (b4 & 1u) ? exp2f(acc[t4][0] * EXP_SC) * linv : 0.f;
        pv[1] = (b4 & 2u) ? exp2f(acc[t4][1] * EXP_SC) * linv : 0.f;
        pv[2] = (b4 & 4u) ? exp2f(acc[t4][2] * EXP_SC) * linv : 0.f;
        pv[3] = (b4 & 8u) ? exp2f(acc[t4][3] * EXP_SC) * linv : 0.f;
        __builtin_nontemporal_store(pv, reinterpret_cast<f32x4*>(
            prow_out + t64 * 64 + t4 * 16));
      }
    }

    // wait the glds (older than the 4 stores above); stores stay in flight
    asm volatile("s_waitcnt vmcnt(4)" ::: "memory");
    __builtin_amdgcn_s_barrier();
  }
}

// ---------------------------------------------------------------------------

extern "C" void kernel_launch(void* const* d_in, const int* in_sizes, int n_in,
                              void* d_out, int out_size, void* d_ws, size_t ws_size,
                              hipStream_t stream) {
  const float* q    = (const float*)d_in[0];
  const float* k    = (const float*)d_in[1];
  const float* v    = (const float*)d_in[2];
  const int*   mask = (const int*)d_in[3];
  const float* Wq   = (const float*)d_in[4];
  const float* bq   = (const float*)d_in[5];
  const float* Wk   = (const float*)d_in[6];
  const float* bk   = (const float*)d_in[7];
  const float* Wv   = (const float*)d_in[8];
  const float* bv   = (const float*)d_in[9];
  const float* Wo   = (const float*)d_in[10];
  const float* bo   = (const float*)d_in[11];

  float* out  = (float*)d_out;                               // [4,2048,1024]
  float* attn = out + (size_t)NB * SEQ * DMODEL;             // [4,16,2048,2048]

  const size_t HSZ = (size_t)NB * NH * SEQ * DK;             // 8,388,608 elems
  const size_t WSZ = (size_t)DMODEL * DMODEL;                // 1,048,576 elems
  short* qhb  = (short*)d_ws;          // 16 MB
  short* khb  = qhb + HSZ;             // 16 MB
  short* vhb  = khb + HSZ;             // 16 MB  (ctxh aliases after transpose_v)
  short* Xbuf = vhb + HSZ;             // 16 MB  (ctxl aliases after projs)
  short* vTb  = Xbuf + HSZ;            // 16 MB
  short* WTq  = vTb + HSZ;             // 2 MB
  short* WTk  = WTq + WSZ;
  short* WTv  = WTk + WSZ;
  short* WToh = WTv + WSZ;
  short* WTol = WToh + WSZ;
  unsigned long long* maskbits = (unsigned long long*)(WTol + WSZ);     // 2 MB
  float* linv_arr = (float*)(maskbits + (size_t)NB * SEQ * (SEQ / 64)); // 0.5 MB
  short* ctxh = vhb;
  short* ctxl = Xbuf;

  const dim3 blk(256);
  const dim3 blk8(512);

  pack_mask_kernel<<<dim3((NB * SEQ * SEQ / 64) / 4), blk, 0, stream>>>(mask, maskbits);

  transpose_w_all_kernel<<<dim3(16, 16, 4), blk, 0, stream>>>(
      Wq, Wk, Wv, Wo, WTq, WTk, WTv, WToh, WTol);

  const int nconv = (int)(NB * SEQ * DMODEL / 8 / 256);      // 4096 blocks
  const int ngemm = 512;                                     // 1-D chunked grid

  convert_f32_bf16_kernel<<<nconv, blk, 0, stream>>>(q, Xbuf);
  proj_mfma_kernel<<<ngemm, blk, 0, stream>>>(Xbuf, WTq, bq, qhb);
  convert_f32_bf16_kernel<<<nconv, blk, 0, stream>>>(k, Xbuf);
  proj_mfma_kernel<<<ngemm, blk, 0, stream>>>(Xbuf, WTk, bk, khb);
  convert_f32_bf16_kernel<<<nconv, blk, 0, stream>>>(v, Xbuf);
  proj_mfma_kernel<<<ngemm, blk, 0, stream>>>(Xbuf, WTv, bv, vhb);

  transpose_v_kernel<<<dim3(SEQ / 64, NB * NH), blk, 0, stream>>>(vhb, vTb);

  const int nattn = (SEQ / 128) * NH * NB;                   // 1024 blocks
  flash_kernel<<<nattn, blk8, 0, stream>>>(qhb, khb, vTb, maskbits,
                                           ctxh, ctxl, linv_arr);
  probs_kernel<<<nattn, blk8, 0, stream>>>(qhb, khb, maskbits, linv_arr, attn);

  outproj_mfma_kernel<<<ngemm, blk, 0, stream>>>(ctxh, ctxl, WToh, WTol, bo, out);
}

// Round 10
// 520.827 us; speedup vs baseline: 1.2683x; 1.2683x over previous
//
#include <hip/hip_runtime.h>

#define NH     16
#define SEQ    2048
#define DMODEL 1024
#define DK     64
#define NB     4

typedef __attribute__((ext_vector_type(8))) short short8v;   // 8 bf16
typedef __attribute__((ext_vector_type(4))) short short4v;   // 4 bf16
typedef __attribute__((ext_vector_type(4))) float f32x4;

// exp(x*0.125) == exp2(x * 0.125*log2(e))
#define EXP_SC 0.18033688011f

__device__ __forceinline__ short f2bf(float x) {
  unsigned u = __float_as_uint(x);
  unsigned r = (u + 0x7FFFu + ((u >> 16) & 1u)) >> 16;
  return (short)r;
}
__device__ __forceinline__ float bf2f(short b) {
  return __uint_as_float(((unsigned)(unsigned short)b) << 16);
}

// async global->LDS, 16 B per lane (dest = wave-uniform base + lane*16)
typedef const __attribute__((address_space(1))) unsigned int* gas_t;
typedef __attribute__((address_space(3))) unsigned int* las_t;
__device__ __forceinline__ void glds16(const void* g, void* l) {
  __builtin_amdgcn_global_load_lds((gas_t)g, (las_t)l, 16, 0, 0);
}

// ---- 256-thread (4-wave) stagers ------------------------------------------
__device__ __forceinline__ void stage_tile(const void* grow0, int gpitchB,
                                           void* ltile, int wid, int lane) {
#pragma unroll
  for (int i = 0; i < 2; ++i) {
    const int row = i * 32 + wid * 8 + (lane >> 3);
    const int srccol = ((lane & 7) * 16) ^ ((lane >> 3) << 4);  // row&7 == lane>>3
    const char* src = reinterpret_cast<const char*>(grow0) + (size_t)row * gpitchB + srccol;
    char* dst = reinterpret_cast<char*>(ltile) + i * 4096 + wid * 1024;
    glds16(src, dst);
  }
}

// ---- 512-thread (8-wave) stagers ------------------------------------------
__device__ __forceinline__ void stage_tile_h8(const void* grow0, int gpitchB,
                                              void* ltile, int wid, int lane) {
  const int row = wid * 8 + (lane >> 3);
  const int srccol = ((lane & 7) * 16) ^ ((lane >> 3) << 4);
  const char* src = reinterpret_cast<const char*>(grow0) + (size_t)row * gpitchB + srccol;
  char* dst = reinterpret_cast<char*>(ltile) + wid * 1024;
  glds16(src, dst);
}
__device__ __forceinline__ void stage_tile128(const void* grow0, int gpitchB,
                                              void* ltile, int wid, int lane) {
#pragma unroll
  for (int i = 0; i < 2; ++i) {
    const int row = i * 64 + wid * 8 + (lane >> 3);
    const int srccol = ((lane & 7) * 16) ^ ((lane >> 3) << 4);
    const char* src = reinterpret_cast<const char*>(grow0) + (size_t)row * gpitchB + srccol;
    char* dst = reinterpret_cast<char*>(ltile) + i * 8192 + wid * 1024;
    glds16(src, dst);
  }
}

// swizzled LDS accessors for [*][64] bf16 tiles (row pitch 128 B)
__device__ __forceinline__ short8v ldfrag(const short* base, int row, int colByte) {
  return *reinterpret_cast<const short8v*>(
      reinterpret_cast<const char*>(base) + row * 128 + (colByte ^ ((row & 7) << 4)));
}
__device__ __forceinline__ void st8b(short* base, int row, int colByte, short4v v) {
  *reinterpret_cast<short4v*>(
      reinterpret_cast<char*>(base) + row * 128 + (colByte ^ ((row & 7) << 4))) = v;
}

// swizzled LDS accessors for [*][64] fp32 tiles (row pitch 256 B)
__device__ __forceinline__ void stPf4(float* base, int row, int colByte, float4 v) {
  *reinterpret_cast<float4*>(
      reinterpret_cast<char*>(base) + row * 256 + (colByte ^ ((row & 7) << 4))) = v;
}
__device__ __forceinline__ float4 ldPf4(const float* base, int row, int colByte) {
  return *reinterpret_cast<const float4*>(
      reinterpret_cast<const char*>(base) + row * 256 + (colByte ^ ((row & 7) << 4)));
}

// ===========================================================================
// pack_mask: [B,S,S] int -> [B,S,S/64] uint64 bitmask
// ===========================================================================
__global__ __launch_bounds__(256) void pack_mask_kernel(
    const int* __restrict__ mask, unsigned long long* __restrict__ bits)
{
  const int t = threadIdx.x;
  const size_t chunk = (size_t)blockIdx.x * 4 + (t >> 6);
  const int lane = t & 63;
  const int m = mask[chunk * 64 + lane];
  const unsigned long long b = __ballot(m != 0);
  if (lane == 0) bits[chunk] = b;
}

// ===========================================================================
// convert fp32 -> bf16 (flat, 8 elems/thread)
// ===========================================================================
__global__ __launch_bounds__(256) void convert_f32_bf16_kernel(
    const float* __restrict__ in, short* __restrict__ out)
{
  const int idx = blockIdx.x * 256 + threadIdx.x;
  const float4 x0 = *reinterpret_cast<const float4*>(&in[(size_t)idx * 8]);
  const float4 x1 = *reinterpret_cast<const float4*>(&in[(size_t)idx * 8 + 4]);
  short8v o;
  o[0] = f2bf(x0.x); o[1] = f2bf(x0.y); o[2] = f2bf(x0.z); o[3] = f2bf(x0.w);
  o[4] = f2bf(x1.x); o[5] = f2bf(x1.y); o[6] = f2bf(x1.z); o[7] = f2bf(x1.w);
  *reinterpret_cast<short8v*>(&out[(size_t)idx * 8]) = o;
}

// ===========================================================================
// transpose all W: z=0..2 -> WT bf16; z=3 -> WTh/WTl hi-lo split (Wo)
// ===========================================================================
__global__ __launch_bounds__(256) void transpose_w_all_kernel(
    const float* __restrict__ W0, const float* __restrict__ W1,
    const float* __restrict__ W2, const float* __restrict__ W3,
    short* __restrict__ WT0, short* __restrict__ WT1,
    short* __restrict__ WT2, short* __restrict__ WT3h, short* __restrict__ WT3l)
{
  __shared__ short Th[64][80];
  __shared__ short Tl[64][80];
  const int t  = threadIdx.x;
  const int k0 = blockIdx.x * 64;
  const int n0 = blockIdx.y * 64;
  const int z  = blockIdx.z;
  const float* W = (z == 0) ? W0 : (z == 1) ? W1 : (z == 2) ? W2 : W3;

  const int kl = t >> 2, nc = (t & 3) * 16;
  if (z < 3) {
#pragma unroll
    for (int i = 0; i < 4; ++i) {
      const float4 x = *reinterpret_cast<const float4*>(&W[(size_t)(k0 + kl) * DMODEL + n0 + nc + i * 4]);
      Th[nc + i * 4 + 0][kl] = f2bf(x.x);
      Th[nc + i * 4 + 1][kl] = f2bf(x.y);
      Th[nc + i * 4 + 2][kl] = f2bf(x.z);
      Th[nc + i * 4 + 3][kl] = f2bf(x.w);
    }
    __syncthreads();
    short* WT = (z == 0) ? WT0 : (z == 1) ? WT1 : WT2;
    const int nl = t >> 2, kc = (t & 3) * 16;
#pragma unroll
    for (int i = 0; i < 2; ++i) {
      const short8v y = *reinterpret_cast<const short8v*>(&Th[nl][kc + i * 8]);
      *reinterpret_cast<short8v*>(&WT[(size_t)(n0 + nl) * DMODEL + k0 + kc + i * 8]) = y;
    }
  } else {
#pragma unroll
    for (int i = 0; i < 4; ++i) {
      const float4 x = *reinterpret_cast<const float4*>(&W[(size_t)(k0 + kl) * DMODEL + n0 + nc + i * 4]);
      const float xv[4] = {x.x, x.y, x.z, x.w};
#pragma unroll
      for (int j = 0; j < 4; ++j) {
        const short hi = f2bf(xv[j]);
        const short lo = f2bf(xv[j] - bf2f(hi));
        Th[nc + i * 4 + j][kl] = hi;
        Tl[nc + i * 4 + j][kl] = lo;
      }
    }
    __syncthreads();
    const int nl = t >> 2, kc = (t & 3) * 16;
#pragma unroll
    for (int i = 0; i < 2; ++i) {
      const short8v yh = *reinterpret_cast<const short8v*>(&Th[nl][kc + i * 8]);
      const short8v yl = *reinterpret_cast<const short8v*>(&Tl[nl][kc + i * 8]);
      *reinterpret_cast<short8v*>(&WT3h[(size_t)(n0 + nl) * DMODEL + k0 + kc + i * 8]) = yh;
      *reinterpret_cast<short8v*>(&WT3l[(size_t)(n0 + nl) * DMODEL + k0 + kc + i * 8]) = yl;
    }
  }
}

// ===========================================================================
// proj MFMA GEMM. 1-D grid, n-fastest + XCD-chunked swizzle.
// ===========================================================================
__global__ __launch_bounds__(256) void proj_mfma_kernel(
    const short* __restrict__ A,   // [8192][1024] bf16
    const short* __restrict__ BT,  // [1024][1024] bf16 (row n = W col n)
    const float* __restrict__ bias,
    short* __restrict__ out)       // [B,H,S,DK] bf16
{
  __shared__ short As[128 * 64];
  __shared__ short Bs[128 * 64];

  const int t = threadIdx.x, lane = t & 63, wid = t >> 6;
  const int g = lane >> 4, r15 = lane & 15;
  const int lid = (blockIdx.x & 7) * 64 + (blockIdx.x >> 3);
  const int m0 = (lid >> 3) * 128, n0 = (lid & 7) * 128;
  const int wm = (wid >> 1) * 64, wn = (wid & 1) * 64;

  f32x4 acc[4][4];
#pragma unroll
  for (int i = 0; i < 4; ++i)
#pragma unroll
    for (int j = 0; j < 4; ++j) acc[i][j] = (f32x4){0.f, 0.f, 0.f, 0.f};

  for (int k0 = 0; k0 < DMODEL; k0 += 64) {
    __syncthreads();
    stage_tile(A + (size_t)m0 * DMODEL + k0, DMODEL * 2, As, wid, lane);
    stage_tile(A + (size_t)(m0 + 64) * DMODEL + k0, DMODEL * 2, As + 64 * 64, wid, lane);
    stage_tile(BT + (size_t)n0 * DMODEL + k0, DMODEL * 2, Bs, wid, lane);
    stage_tile(BT + (size_t)(n0 + 64) * DMODEL + k0, DMODEL * 2, Bs + 64 * 64, wid, lane);
    __syncthreads();

#pragma unroll
    for (int w = 0; w < 2; ++w) {
      short8v a[4], b[4];
#pragma unroll
      for (int i = 0; i < 4; ++i) a[i] = ldfrag(As, wm + i * 16 + r15, w * 64 + g * 16);
#pragma unroll
      for (int j = 0; j < 4; ++j) b[j] = ldfrag(Bs, wn + j * 16 + r15, w * 64 + g * 16);
#pragma unroll
      for (int i = 0; i < 4; ++i)
#pragma unroll
        for (int j = 0; j < 4; ++j)
          acc[i][j] = __builtin_amdgcn_mfma_f32_16x16x32_bf16(a[i], b[j], acc[i][j], 0, 0, 0);
    }
  }

#pragma unroll
  for (int j = 0; j < 4; ++j) {
    const int n = n0 + wn + j * 16 + r15;
    const int hh = n >> 6, dd = n & 63;
    const float bv = bias[n];
#pragma unroll
    for (int i = 0; i < 4; ++i) {
#pragma unroll
      for (int reg = 0; reg < 4; ++reg) {
        const int m = m0 + wm + i * 16 + g * 4 + reg;
        const int bb = m >> 11, ss = m & 2047;
        out[((size_t)(bb * NH + hh) * SEQ + ss) * DK + dd] = f2bf(acc[i][j][reg] + bv);
      }
    }
  }
}

// ===========================================================================
// outproj bf16x3 MFMA. Same 1-D chunked grid as proj.
// ===========================================================================
__global__ __launch_bounds__(256) void outproj_mfma_kernel(
    const short* __restrict__ Ahp, const short* __restrict__ Alp,
    const short* __restrict__ BTh, const short* __restrict__ BTl,
    const float* __restrict__ bias, float* __restrict__ out)
{
  __shared__ short Ah[128 * 64];
  __shared__ short Al[128 * 64];
  __shared__ short Bh[128 * 64];
  __shared__ short Bl[128 * 64];

  const int t = threadIdx.x, lane = t & 63, wid = t >> 6;
  const int g = lane >> 4, r15 = lane & 15;
  const int lid = (blockIdx.x & 7) * 64 + (blockIdx.x >> 3);
  const int m0 = (lid >> 3) * 128, n0 = (lid & 7) * 128;
  const int wm = (wid >> 1) * 64, wn = (wid & 1) * 64;

  f32x4 acc[4][4];
#pragma unroll
  for (int i = 0; i < 4; ++i)
#pragma unroll
    for (int j = 0; j < 4; ++j) acc[i][j] = (f32x4){0.f, 0.f, 0.f, 0.f};

  for (int k0 = 0; k0 < DMODEL; k0 += 64) {
    __syncthreads();
    stage_tile(Ahp + (size_t)m0 * DMODEL + k0, DMODEL * 2, Ah, wid, lane);
    stage_tile(Ahp + (size_t)(m0 + 64) * DMODEL + k0, DMODEL * 2, Ah + 64 * 64, wid, lane);
    stage_tile(Alp + (size_t)m0 * DMODEL + k0, DMODEL * 2, Al, wid, lane);
    stage_tile(Alp + (size_t)(m0 + 64) * DMODEL + k0, DMODEL * 2, Al + 64 * 64, wid, lane);
    stage_tile(BTh + (size_t)n0 * DMODEL + k0, DMODEL * 2, Bh, wid, lane);
    stage_tile(BTh + (size_t)(n0 + 64) * DMODEL + k0, DMODEL * 2, Bh + 64 * 64, wid, lane);
    stage_tile(BTl + (size_t)n0 * DMODEL + k0, DMODEL * 2, Bl, wid, lane);
    stage_tile(BTl + (size_t)(n0 + 64) * DMODEL + k0, DMODEL * 2, Bl + 64 * 64, wid, lane);
    __syncthreads();

#pragma unroll
    for (int w = 0; w < 2; ++w) {
      short8v ah[4], al[4];
#pragma unroll
      for (int i = 0; i < 4; ++i) {
        ah[i] = ldfrag(Ah, wm + i * 16 + r15, w * 64 + g * 16);
        al[i] = ldfrag(Al, wm + i * 16 + r15, w * 64 + g * 16);
      }
#pragma unroll
      for (int j = 0; j < 4; ++j) {
        const short8v bh = ldfrag(Bh, wn + j * 16 + r15, w * 64 + g * 16);
        const short8v bl = ldfrag(Bl, wn + j * 16 + r15, w * 64 + g * 16);
#pragma unroll
        for (int i = 0; i < 4; ++i) {
          acc[i][j] = __builtin_amdgcn_mfma_f32_16x16x32_bf16(ah[i], bh, acc[i][j], 0, 0, 0);
          acc[i][j] = __builtin_amdgcn_mfma_f32_16x16x32_bf16(ah[i], bl, acc[i][j], 0, 0, 0);
          acc[i][j] = __builtin_amdgcn_mfma_f32_16x16x32_bf16(al[i], bh, acc[i][j], 0, 0, 0);
        }
      }
    }
  }

#pragma unroll
  for (int j = 0; j < 4; ++j) {
    const int n = n0 + wn + j * 16 + r15;
    const float bv = bias[n];
#pragma unroll
    for (int i = 0; i < 4; ++i)
#pragma unroll
      for (int reg = 0; reg < 4; ++reg) {
        const int m = m0 + wm + i * 16 + g * 4 + reg;
        out[(size_t)m * DMODEL + n] = acc[i][j][reg] + bv;
      }
  }
}

// ===========================================================================
// transpose V: vhb [head][s][d] -> vT [head][d][s]   (bf16)
// ===========================================================================
__global__ __launch_bounds__(256) void transpose_v_kernel(
    const short* __restrict__ vhb, short* __restrict__ vT)
{
  __shared__ short T[64][72];
  const int t    = threadIdx.x;
  const int s0   = blockIdx.x * 64;
  const int head = blockIdx.y;
  const size_t ibase = (size_t)head * SEQ * DK;
  const size_t obase = (size_t)head * DK * SEQ;

  const int sl = t >> 2, d0 = (t & 3) * 16;
#pragma unroll
  for (int i = 0; i < 2; ++i) {
    const short8v x = *reinterpret_cast<const short8v*>(
        &vhb[ibase + (size_t)(s0 + sl) * DK + d0 + i * 8]);
#pragma unroll
    for (int j = 0; j < 8; ++j) T[d0 + i * 8 + j][sl] = x[j];
  }
  __syncthreads();
  const int dl = t >> 2, soff = (t & 3) * 16;
#pragma unroll
  for (int i = 0; i < 2; ++i) {
    const short8v y = *reinterpret_cast<const short8v*>(&T[dl][soff + i * 8]);
    *reinterpret_cast<short8v*>(&vT[obase + (size_t)dl * SEQ + s0 + soff + i * 8]) = y;
  }
}

// ===========================================================================
// flash_kernel: QBLK=128, 8 waves, m==0 single pass, K/V dbuf, XCD swizzle.
// ===========================================================================
__global__ __launch_bounds__(512) void flash_kernel(
    const short* __restrict__ qh, const short* __restrict__ kh,
    const short* __restrict__ vT, const unsigned long long* __restrict__ maskbits,
    short* __restrict__ ctxh, short* __restrict__ ctxl,
    float* __restrict__ linv_arr)
{
  __shared__ short Qs[128 * 64];      // 16 KB
  __shared__ short Ks[2][64 * 64];    // 16 KB
  __shared__ short VsT[2][64 * 64];   // 16 KB
  __shared__ short Psb[128 * 64];     // 16 KB (wave-private rows)

  const int t    = threadIdx.x;
  const int lane = t & 63;
  const int wid  = t >> 6;            // 0..7
  const int g    = lane >> 4;
  const int r15  = lane & 15;
  const int qbase = wid * 16;
  const int qrow  = qbase + r15;

  const int bid = blockIdx.x;
  const int swz = (bid & 7) * 128 + (bid >> 3);
  const int qt = swz & 15;
  const int h  = (swz >> 4) & 15;
  const int b  = swz >> 8;
  const int q0 = qt * 128;

  const size_t headbase = ((size_t)(b * NH + h)) * SEQ * DK;
  const size_t vTbase   = ((size_t)(b * NH + h)) * DK * SEQ;
  const size_t mrow     = ((size_t)b * SEQ + (q0 + qrow)) * (SEQ / 64);

  stage_tile128(qh + headbase + (size_t)q0 * DK, DK * 2, Qs, wid, lane);
  stage_tile_h8(kh + headbase, DK * 2, Ks[0], wid, lane);
  stage_tile_h8(reinterpret_cast<const char*>(vT + vTbase), SEQ * 2, VsT[0], wid, lane);
  asm volatile("s_waitcnt vmcnt(0)" ::: "memory");
  __builtin_amdgcn_s_barrier();

  const short8v bQ0 = ldfrag(Qs, qrow, g * 16);
  const short8v bQ1 = ldfrag(Qs, qrow, 64 + g * 16);

  float lsum = 0.f;
  f32x4 cacc[4];
#pragma unroll
  for (int i = 0; i < 4; ++i) cacc[i] = (f32x4){0.f, 0.f, 0.f, 0.f};

  for (int t64 = 0; t64 < 32; ++t64) {
    const int cur = t64 & 1;
    if (t64 < 31) {
      stage_tile_h8(kh + headbase + (size_t)(t64 + 1) * 64 * DK, DK * 2,
                    Ks[cur ^ 1], wid, lane);
      stage_tile_h8(reinterpret_cast<const char*>(vT + vTbase + (t64 + 1) * 64), SEQ * 2,
                    VsT[cur ^ 1], wid, lane);
    }
    __builtin_amdgcn_sched_barrier(0);

    f32x4 acc[4];
#pragma unroll
    for (int t4 = 0; t4 < 4; ++t4) acc[t4] = (f32x4){0.f, 0.f, 0.f, 0.f};
#pragma unroll
    for (int t4 = 0; t4 < 4; ++t4) {
      const short8v aK0 = ldfrag(Ks[cur], t4 * 16 + r15, g * 16);
      const short8v aK1 = ldfrag(Ks[cur], t4 * 16 + r15, 64 + g * 16);
      acc[t4] = __builtin_amdgcn_mfma_f32_16x16x32_bf16(aK0, bQ0, acc[t4], 0, 0, 0);
      acc[t4] = __builtin_amdgcn_mfma_f32_16x16x32_bf16(aK1, bQ1, acc[t4], 0, 0, 0);
    }

    const unsigned long long mb = maskbits[mrow + t64];
    if (__all(mb == ~0ULL)) {
#pragma unroll
      for (int t4 = 0; t4 < 4; ++t4) {
        short4v pk;
#pragma unroll
        for (int reg = 0; reg < 4; ++reg) {
          const float p = exp2f(acc[t4][reg] * EXP_SC);
          lsum += p;
          pk[reg] = f2bf(p);
        }
        st8b(Psb, qrow, t4 * 32 + g * 8, pk);
      }
    } else {
#pragma unroll
      for (int t4 = 0; t4 < 4; ++t4) {
        const unsigned b4 = (unsigned)(mb >> (t4 * 16 + g * 4)) & 0xFu;
        short4v pk;
#pragma unroll
        for (int reg = 0; reg < 4; ++reg) {
          const float p = ((b4 >> reg) & 1u) ? exp2f(acc[t4][reg] * EXP_SC) : 0.f;
          lsum += p;
          pk[reg] = f2bf(p);
        }
        st8b(Psb, qrow, t4 * 32 + g * 8, pk);
      }
    }

    // PV (Psb rows are wave-private)
    {
      const short8v aP0 = ldfrag(Psb, qrow, g * 16);
      const short8v aP1 = ldfrag(Psb, qrow, 64 + g * 16);
#pragma unroll
      for (int dt = 0; dt < 4; ++dt) {
        const short8v bV0 = ldfrag(VsT[cur], dt * 16 + r15, g * 16);
        const short8v bV1 = ldfrag(VsT[cur], dt * 16 + r15, 64 + g * 16);
        cacc[dt] = __builtin_amdgcn_mfma_f32_16x16x32_bf16(aP0, bV0, cacc[dt], 0, 0, 0);
        cacc[dt] = __builtin_amdgcn_mfma_f32_16x16x32_bf16(aP1, bV1, cacc[dt], 0, 0, 0);
      }
    }

    asm volatile("s_waitcnt vmcnt(0)" ::: "memory");
    __builtin_amdgcn_s_barrier();
  }

  float l = lsum;
  l += __shfl_xor(l, 16);
  l += __shfl_xor(l, 32);
  const float linv = 1.0f / l;
  if (g == 0)
    linv_arr[(size_t)(b * NH + h) * SEQ + q0 + qrow] = linv;

  float linvr[4];
#pragma unroll
  for (int reg = 0; reg < 4; ++reg) linvr[reg] = __shfl(linv, g * 4 + reg);

#pragma unroll
  for (int dt = 0; dt < 4; ++dt)
#pragma unroll
    for (int reg = 0; reg < 4; ++reg) {
      const float x = cacc[dt][reg] * linvr[reg];
      const short hi = f2bf(x);
      const short lo = f2bf(x - bf2f(hi));
      const size_t off = (size_t)(b * SEQ + q0 + qbase + g * 4 + reg) * DMODEL
                       + h * DK + dt * 16 + r15;
      ctxh[off] = hi;
      ctxl[off] = lo;
    }
}

// ===========================================================================
// probs_kernel (R8 structure): QBLK=128, 8 waves, LDS bounce for 256B-segment
// coalesced nt stores; p = exp2(fma(s, c, log2(linv))); dbuf K; counted vmcnt.
// ===========================================================================
__global__ __launch_bounds__(512) void probs_kernel(
    const short* __restrict__ qh, const short* __restrict__ kh,
    const unsigned long long* __restrict__ maskbits,
    const float* __restrict__ linv_arr,
    float* __restrict__ attn_out)
{
  __shared__ short Qs[128 * 64];     // 16 KB
  __shared__ short Ks[2][64 * 64];   // 16 KB
  __shared__ float PsbF[128 * 64];   // 32 KB, swizzled fp32, wave-private rows

  const int t    = threadIdx.x;
  const int lane = t & 63;
  const int wid  = t >> 6;           // 0..7
  const int g    = lane >> 4;
  const int r15  = lane & 15;
  const int qbase = wid * 16;
  const int qrow  = qbase + r15;

  const int bid = blockIdx.x;
  const int swz = (bid & 7) * 128 + (bid >> 3);
  const int qt = swz & 15;
  const int h  = (swz >> 4) & 15;
  const int b  = swz >> 8;
  const int q0 = qt * 128;

  const size_t headbase = ((size_t)(b * NH + h)) * SEQ * DK;
  const size_t attnbase = ((size_t)(b * NH + h)) * SEQ * SEQ;
  const size_t mrow     = ((size_t)b * SEQ + (q0 + qrow)) * (SEQ / 64);

  const float linv  = linv_arr[(size_t)(b * NH + h) * SEQ + q0 + qrow];
  const float llinv = log2f(linv);

  stage_tile128(qh + headbase + (size_t)q0 * DK, DK * 2, Qs, wid, lane);
  stage_tile_h8(kh + headbase, DK * 2, Ks[0], wid, lane);
  asm volatile("s_waitcnt vmcnt(0)" ::: "memory");
  __builtin_amdgcn_s_barrier();

  const short8v bQ0 = ldfrag(Qs, qrow, g * 16);
  const short8v bQ1 = ldfrag(Qs, qrow, 64 + g * 16);

  for (int t64 = 0; t64 < 32; ++t64) {
    const int cur = t64 & 1;
    if (t64 + 1 < 32)
      stage_tile_h8(kh + headbase + (size_t)(t64 + 1) * 64 * DK, DK * 2,
                    Ks[cur ^ 1], wid, lane);
    __builtin_amdgcn_sched_barrier(0);

    f32x4 acc[4];
#pragma unroll
    for (int t4 = 0; t4 < 4; ++t4) acc[t4] = (f32x4){0.f, 0.f, 0.f, 0.f};
#pragma unroll
    for (int t4 = 0; t4 < 4; ++t4) {
      const short8v aK0 = ldfrag(Ks[cur], t4 * 16 + r15, g * 16);
      const short8v aK1 = ldfrag(Ks[cur], t4 * 16 + r15, 64 + g * 16);
      acc[t4] = __builtin_amdgcn_mfma_f32_16x16x32_bf16(aK0, bQ0, acc[t4], 0, 0, 0);
      acc[t4] = __builtin_amdgcn_mfma_f32_16x16x32_bf16(aK1, bQ1, acc[t4], 0, 0, 0);
    }

    const unsigned long long mb = maskbits[mrow + t64];
    if (__all(mb == ~0ULL)) {
#pragma unroll
      for (int t4 = 0; t4 < 4; ++t4) {
        float4 pv;
        pv.x = exp2f(fmaf(acc[t4][0], EXP_SC, llinv));
        pv.y = exp2f(fmaf(acc[t4][1], EXP_SC, llinv));
        pv.z = exp2f(fmaf(acc[t4][2], EXP_SC, llinv));
        pv.w = exp2f(fmaf(acc[t4][3], EXP_SC, llinv));
        stPf4(PsbF, qrow, t4 * 64 + g * 16, pv);
      }
    } else {
#pragma unroll
      for (int t4 = 0; t4 < 4; ++t4) {
        const unsigned b4 = (unsigned)(mb >> (t4 * 16 + g * 4)) & 0xFu;
        float4 pv;
        pv.x = (b4 & 1u) ? exp2f(acc[t4][0] * EXP_SC) * linv : 0.f;
        pv.y = (b4 & 2u) ? exp2f(acc[t4][1] * EXP_SC) * linv : 0.f;
        pv.z = (b4 & 4u) ? exp2f(acc[t4][2] * EXP_SC) * linv : 0.f;
        pv.w = (b4 & 8u) ? exp2f(acc[t4][3] * EXP_SC) * linv : 0.f;
        stPf4(PsbF, qrow, t4 * 64 + g * 16, pv);
      }
    }

    // read back own wave's rows and nontemporal-store fp32 probs (256B segs)
#pragma unroll
    for (int i = 0; i < 4; ++i) {
      const int prow = qbase + i * 4 + g;
      const float4 f = ldPf4(PsbF, prow, r15 * 16);
      f32x4 fv; fv[0] = f.x; fv[1] = f.y; fv[2] = f.z; fv[3] = f.w;
      __builtin_nontemporal_store(fv, reinterpret_cast<f32x4*>(
          &attn_out[attnbase + (size_t)(q0 + prow) * SEQ + t64 * 64 + r15 * 4]));
    }

    // wait the 1 glds (oldest); leave the 4 stores in flight
    asm volatile("s_waitcnt vmcnt(4)" ::: "memory");
    __builtin_amdgcn_s_barrier();
  }
}

// ---------------------------------------------------------------------------

extern "C" void kernel_launch(void* const* d_in, const int* in_sizes, int n_in,
                              void* d_out, int out_size, void* d_ws, size_t ws_size,
                              hipStream_t stream) {
  const float* q    = (const float*)d_in[0];
  const float* k    = (const float*)d_in[1];
  const float* v    = (const float*)d_in[2];
  const int*   mask = (const int*)d_in[3];
  const float* Wq   = (const float*)d_in[4];
  const float* bq   = (const float*)d_in[5];
  const float* Wk   = (const float*)d_in[6];
  const float* bk   = (const float*)d_in[7];
  const float* Wv   = (const float*)d_in[8];
  const float* bv   = (const float*)d_in[9];
  const float* Wo   = (const float*)d_in[10];
  const float* bo   = (const float*)d_in[11];

  float* out  = (float*)d_out;                               // [4,2048,1024]
  float* attn = out + (size_t)NB * SEQ * DMODEL;             // [4,16,2048,2048]

  const size_t HSZ = (size_t)NB * NH * SEQ * DK;             // 8,388,608 elems
  const size_t WSZ = (size_t)DMODEL * DMODEL;                // 1,048,576 elems
  short* qhb  = (short*)d_ws;          // 16 MB
  short* khb  = qhb + HSZ;             // 16 MB
  short* vhb  = khb + HSZ;             // 16 MB  (ctxh aliases after transpose_v)
  short* Xbuf = vhb + HSZ;             // 16 MB  (ctxl aliases after projs)
  short* vTb  = Xbuf + HSZ;            // 16 MB
  short* WTq  = vTb + HSZ;             // 2 MB
  short* WTk  = WTq + WSZ;
  short* WTv  = WTk + WSZ;
  short* WToh = WTv + WSZ;
  short* WTol = WToh + WSZ;
  unsigned long long* maskbits = (unsigned long long*)(WTol + WSZ);     // 2 MB
  float* linv_arr = (float*)(maskbits + (size_t)NB * SEQ * (SEQ / 64)); // 0.5 MB
  short* ctxh = vhb;
  short* ctxl = Xbuf;

  const dim3 blk(256);
  const dim3 blk8(512);

  pack_mask_kernel<<<dim3((NB * SEQ * SEQ / 64) / 4), blk, 0, stream>>>(mask, maskbits);

  transpose_w_all_kernel<<<dim3(16, 16, 4), blk, 0, stream>>>(
      Wq, Wk, Wv, Wo, WTq, WTk, WTv, WToh, WTol);

  const int nconv = (int)(NB * SEQ * DMODEL / 8 / 256);      // 4096 blocks
  const int ngemm = 512;                                     // 1-D chunked grid

  convert_f32_bf16_kernel<<<nconv, blk, 0, stream>>>(q, Xbuf);
  proj_mfma_kernel<<<ngemm, blk, 0, stream>>>(Xbuf, WTq, bq, qhb);
  convert_f32_bf16_kernel<<<nconv, blk, 0, stream>>>(k, Xbuf);
  proj_mfma_kernel<<<ngemm, blk, 0, stream>>>(Xbuf, WTk, bk, khb);
  convert_f32_bf16_kernel<<<nconv, blk, 0, stream>>>(v, Xbuf);
  proj_mfma_kernel<<<ngemm, blk, 0, stream>>>(Xbuf, WTv, bv, vhb);

  transpose_v_kernel<<<dim3(SEQ / 64, NB * NH), blk, 0, stream>>>(vhb, vTb);

  const int nattn = (SEQ / 128) * NH * NB;                   // 1024 blocks
  flash_kernel<<<nattn, blk8, 0, stream>>>(qhb, khb, vTb, maskbits,
                                           ctxh, ctxl, linv_arr);
  probs_kernel<<<nattn, blk8, 0, stream>>>(qhb, khb, maskbits, linv_arr, attn);

  outproj_mfma_kernel<<<ngemm, blk, 0, stream>>>(ctxh, ctxl, WToh, WTol, bo, out);
}